// Round 1
// 248.290 us; speedup vs baseline: 1.0055x; 1.0055x over previous
//
#include <hip/hip_runtime.h>
#include <math.h>

// Problem constants (from reference): B=64, C=64, L=8192, fp32.
#define BB 64
#define CC 64
#define LL 8192
#define EPS_F 1.1920928955078125e-07f  // np.finfo(np.float32).eps
#define SPLITS 32                       // stats blocks per batch

// Normalize decomposition: each block handles 2048 float4 (8 iters x 256 thr)
#define NORM_BLOCKS_PER_B 64            // (C*L/4) / 2048 = 64
#define NB_NORM (BB * NORM_BLOCKS_PER_B) // 4096 normalize blocks
#define NB_AUX  512                      // B*L/4/256 idx-convert blocks

typedef float f4 __attribute__((ext_vector_type(4)));
typedef int   i4 __attribute__((ext_vector_type(4)));

// d_ws layout: partials[b][s] = float2{sum, sumsq}, 64*32 slots (16 KB).
// Every slot is written by tln_stats -> no zeroing pass, no atomics.

// ---------------------------------------------------------------------------
// Kernel 1: per-(b,s) partial {sum, sumsq} over prefix data[b, :, :zp[b]].
// Grid (B, SPLITS) x 256. Block (b,s) handles rows c = s, s+SPLITS (2 rows).
// Regular (caching) loads on purpose: they warm L3 with the prefix, which
// kernel 2 re-reads. Kernel 2's stores are non-temporal so this stays warm.
// ---------------------------------------------------------------------------
__global__ __launch_bounds__(256) void tln_stats(const float* __restrict__ data,
                          const int* __restrict__ zero_pos,
                          float2* __restrict__ partials) {
    const int b = blockIdx.x;
    const int s = blockIdx.y;
    const int tid = threadIdx.x;           // 0..255
    const int zp = zero_pos[b];
    const int nv = zp >> 2;                // full float4's per row
    const float* base = data + (size_t)b * CC * LL;

    float sum = 0.0f, sq = 0.0f;
    for (int c = s; c < CC; c += SPLITS) {
        const float* rowp = base + (size_t)c * LL;
        const f4* row4 = (const f4*)rowp;   // L=8192 -> 16B aligned
        for (int i = tid; i < nv; i += 256) {
            f4 v = row4[i];
            sum += v.x + v.y + v.z + v.w;
            sq  += v.x * v.x + v.y * v.y + v.z * v.z + v.w * v.w;
        }
        // scalar tail (at most 3 elements)
        for (int l = (nv << 2) + tid; l < zp; l += 256) {
            float v = rowp[l];
            sum += v;
            sq  += v * v;
        }
    }

    // wave-64 reduce, then cross-wave via LDS
    #pragma unroll
    for (int off = 32; off > 0; off >>= 1) {
        sum += __shfl_down(sum, off);
        sq  += __shfl_down(sq, off);
    }
    __shared__ float lsum[4], lsq[4];
    const int wave = tid >> 6;
    const int lane = tid & 63;
    if (lane == 0) { lsum[wave] = sum; lsq[wave] = sq; }
    __syncthreads();
    if (tid == 0) {
        float2 p;
        p.x = lsum[0] + lsum[1] + lsum[2] + lsum[3];
        p.y = lsq[0] + lsq[1] + lsq[2] + lsq[3];
        partials[b * SPLITS + s] = p;
    }
}

// ---------------------------------------------------------------------------
// Kernel 2 (fused): blocks [0, NB_NORM) normalize the slab; each block does
// 2048 consecutive float4 (8 per thread), recomputing mean/inv from the 32
// L2-hot partials with an all-lane shfl_xor reduce (no LDS, no barrier).
// Output stores are NON-TEMPORAL: they bypass/deprioritize L3 so the data
// prefix cached by tln_stats stays resident and is re-read from L3, not HBM.
// Blocks [NB_NORM, NB_NORM+NB_AUX) convert idxes->float and write zero_pos.
// ---------------------------------------------------------------------------
__global__ __launch_bounds__(256) void tln_fused(const f4* __restrict__ data4,
                          const float2* __restrict__ partials,
                          const int* __restrict__ zero_pos,
                          const i4* __restrict__ idxes,
                          f4* __restrict__ out4,
                          f4* __restrict__ out_idx,
                          float* __restrict__ out_zp) {
    const int blk = blockIdx.x;
    const int tid = threadIdx.x;

    if (blk < NB_NORM) {
        const int b = blk >> 6;            // NORM_BLOCKS_PER_B = 64
        const int t = blk & 63;
        const int lane = tid & 63;

        // every lane loads one of the 32 partials (halves duplicate), then a
        // 5-step xor-butterfly gives every lane the full {sum, sumsq}
        float2 p = partials[(b << 5) + (lane & 31)];
        float s_ = p.x, q_ = p.y;
        #pragma unroll
        for (int off = 16; off > 0; off >>= 1) {
            s_ += __shfl_xor(s_, off);
            q_ += __shfl_xor(q_, off);
        }
        const float cnt  = (float)CC * (float)zero_pos[b];
        const float mean = s_ / cnt;
        const float var  = (q_ - cnt * mean * mean) / (cnt - 1.0f);
        const float inv  = 1.0f / (sqrtf(var) + EPS_F);

        // b*131072 + t*2048 + tid  (disjoint bit fields)
        const size_t base = ((size_t)b << 17) | ((size_t)t << 11) | (size_t)tid;
        #pragma unroll
        for (int k = 0; k < 8; ++k) {
            const size_t i = base + ((size_t)k << 8);
            f4 v = data4[i];                     // cached load: prefix hits L3
            f4 o = (v - mean) * inv;
            __builtin_nontemporal_store(o, out4 + i);  // streaming store
        }
    } else {
        const int j = blk - NB_NORM;
        const int i = j * 256 + tid;       // < 131072
        i4 v = idxes[i];
        f4 o = __builtin_convertvector(v, f4);
        __builtin_nontemporal_store(o, out_idx + i);
        if (j == 0 && tid < BB) out_zp[tid] = (float)zero_pos[tid];
    }
}

extern "C" void kernel_launch(void* const* d_in, const int* in_sizes, int n_in,
                              void* d_out, int out_size, void* d_ws, size_t ws_size,
                              hipStream_t stream) {
    const float* data    = (const float*)d_in[0];
    const int* idxes     = (const int*)d_in[1];
    const int* zero_pos  = (const int*)d_in[2];

    float2* partials = (float2*)d_ws;       // B*SPLITS slots, all overwritten

    float* out_data = (float*)d_out;                        // B*C*L
    float* out_idx  = out_data + (size_t)BB * CC * LL;      // B*L
    float* out_zp   = out_idx + (size_t)BB * LL;            // B

    tln_stats<<<dim3(BB, SPLITS), 256, 0, stream>>>(data, zero_pos, partials);

    tln_fused<<<NB_NORM + NB_AUX, 256, 0, stream>>>(
        (const f4*)data, partials, zero_pos, (const i4*)idxes,
        (f4*)out_data, (f4*)out_idx, out_zp);
}